// Round 2
// baseline (331.308 us; speedup 1.0000x reference)
//
#include <hip/hip_runtime.h>
#include <cstddef>

#define E 512
#define H 8
#define D 64
#define BATCH 2
#define SEQ 4096

typedef __attribute__((ext_vector_type(8))) short bf16x8;   // MFMA A/B frag
typedef __attribute__((ext_vector_type(4))) float f32x4;    // 16x16 C/D frag
typedef __attribute__((ext_vector_type(16))) float f32x16;  // 32x32 C/D frag
typedef __attribute__((ext_vector_type(4))) unsigned uint4v;

__device__ __forceinline__ ushort f2bf(float f) {
  unsigned u = __builtin_bit_cast(unsigned, f);
  u += 0x7fff + ((u >> 16) & 1);  // RNE
  return (ushort)(u >> 16);
}
__device__ __forceinline__ float bf2f(ushort h) {
  return __builtin_bit_cast(float, (unsigned)h << 16);
}
__device__ __forceinline__ unsigned pk_bf16(float lo, float hi) {
#if __has_builtin(__builtin_amdgcn_cvt_pk_bf16_f32)
  typedef __attribute__((ext_vector_type(2))) __bf16 bfv2;
  bfv2 r = __builtin_amdgcn_cvt_pk_bf16_f32(lo, hi);
  return __builtin_bit_cast(unsigned, r);
#else
  return (unsigned)f2bf(lo) | ((unsigned)f2bf(hi) << 16);
#endif
}
__device__ __forceinline__ float fexp2(float x) {
#if __has_builtin(__builtin_amdgcn_exp2f)
  return __builtin_amdgcn_exp2f(x);
#else
  return exp2f(x);
#endif
}
// lanes[32:63] of a  <->  lanes[0:31] of b
__device__ __forceinline__ void permswap32(unsigned& a, unsigned& b) {
  asm volatile("v_permlane32_swap_b32 %0, %1" : "+v"(a), "+v"(b));
}

// ---------------------------------------------------------------------------
// Kernel 0: cast x -> bf16 hi/lo split (xh + xl ~= x to ~16 mantissa bits)
// ---------------------------------------------------------------------------
__global__ __launch_bounds__(256) void xcast(const float* __restrict__ x,
                                             ushort* __restrict__ xh,
                                             ushort* __restrict__ xl) {
  size_t i = ((size_t)blockIdx.x * 256 + threadIdx.x) * 4;
  float4 v = *(const float4*)&x[i];
  ushort4 h, l;
  h.x = f2bf(v.x); l.x = f2bf(v.x - bf2f(h.x));
  h.y = f2bf(v.y); l.y = f2bf(v.y - bf2f(h.y));
  h.z = f2bf(v.z); l.z = f2bf(v.z - bf2f(h.z));
  h.w = f2bf(v.w); l.w = f2bf(v.w - bf2f(h.w));
  *(ushort4*)&xh[i] = h;
  *(ushort4*)&xl[i] = l;
}

// ---------------------------------------------------------------------------
// Kernel 1a: fold weights. Block = 256 k-lanes x 8 n (8 fp32 accs).
// ---------------------------------------------------------------------------
__global__ __launch_bounds__(256) void fold_tiled(
    const float* __restrict__ wq, const float* __restrict__ wk,
    const float* __restrict__ rot, const float* __restrict__ ent,
    ushort* __restrict__ weffbT) {
  const int which = blockIdx.z;
  const float* w = which ? wk : wq;
  const float* r = which ? ent : rot;
  const int k = blockIdx.x * 256 + threadIdx.x;
  const int n0 = blockIdx.y * 8;
  float acc[8] = {};
  for (int j0 = 0; j0 < E; j0 += 16) {
    float wv_[16];
#pragma unroll
    for (int u = 0; u < 16; ++u) wv_[u] = w[(size_t)(j0 + u) * E + k];
#pragma unroll
    for (int u = 0; u < 16; ++u)
#pragma unroll
      for (int t = 0; t < 8; ++t)
        acc[t] += wv_[u] * r[(size_t)(j0 + u) * E + n0 + t];
  }
#pragma unroll
  for (int t = 0; t < 8; ++t)
    weffbT[(size_t)which * E * E + (size_t)(n0 + t) * E + k] = f2bf(acc[t]);
}

// Kernel 1b: weffT[2][n][k] = bf16(wv[n][k]) — identity layout, pure cast.
__global__ __launch_bounds__(256) void wv_cast(const float* __restrict__ wv,
                                               ushort* __restrict__ dst) {
  size_t i = ((size_t)blockIdx.x * 256 + threadIdx.x) * 4;
  float4 v = *(const float4*)&wv[i];
  ushort4 o;
  o.x = f2bf(v.x); o.y = f2bf(v.y); o.z = f2bf(v.z); o.w = f2bf(v.w);
  *(ushort4*)&dst[i] = o;
}

// ---------------------------------------------------------------------------
// Kernel 2: fused QKV GEMM (unchanged; software-pipelined staging).
// ---------------------------------------------------------------------------
#define LDA 40  // padded LDS stride (bf16): 80B

__global__ __launch_bounds__(256) void qkv_fused(
    const ushort* __restrict__ xhg, const ushort* __restrict__ xlg,
    const ushort* __restrict__ weffbT, ushort* __restrict__ qg,
    ushort* __restrict__ kg, ushort* __restrict__ vtg) {
  __shared__ ushort sm[5 * 64 * LDA];  // Ah | Al | B0 | B1 | B2
  ushort* Ah = sm;
  ushort* Al = sm + 64 * LDA;
  ushort* Bs = sm + 2 * 64 * LDA;
  ushort* vt_tile = Bs;  // epilogue reuse: 64*72 <= 3*64*40

  const int head = blockIdx.x;
  const int m0 = blockIdx.y * 64;
  const int tid = threadIdx.x;
  const int wave = tid >> 6, lane = tid & 63;
  const int l15 = lane & 15, quad = lane >> 4;
  const int ar = tid >> 2, ac8 = (tid & 3) * 8;  // 64x32 tile staging slot

  const ushort* arow = xhg + (size_t)(m0 + ar) * E + ac8;
  const ushort* lrow = xlg + (size_t)(m0 + ar) * E + ac8;
  const ushort* b0row = weffbT + (size_t)(head * 64 + ar) * E + ac8;

  f32x4 acc[3][4];
#pragma unroll
  for (int w = 0; w < 3; ++w)
#pragma unroll
    for (int nt = 0; nt < 4; ++nt) acc[w][nt] = (f32x4){0.f, 0.f, 0.f, 0.f};

  // preload tile k0=0
  uint4 pa_h = *(const uint4*)&arow[0];
  uint4 pa_l = *(const uint4*)&lrow[0];
  uint4 pb0 = *(const uint4*)&b0row[0];
  uint4 pb1 = *(const uint4*)&b0row[E * E];
  uint4 pb2 = *(const uint4*)&b0row[2 * E * E];

  for (int k0 = 0; k0 < E; k0 += 32) {
    __syncthreads();
    *(uint4*)&Ah[ar * LDA + ac8] = pa_h;
    *(uint4*)&Al[ar * LDA + ac8] = pa_l;
    *(uint4*)&Bs[0 * 64 * LDA + ar * LDA + ac8] = pb0;
    *(uint4*)&Bs[1 * 64 * LDA + ar * LDA + ac8] = pb1;
    *(uint4*)&Bs[2 * 64 * LDA + ar * LDA + ac8] = pb2;
    __syncthreads();

    const int kn = (k0 + 32 < E) ? k0 + 32 : 0;
    pa_h = *(const uint4*)&arow[kn];
    pa_l = *(const uint4*)&lrow[kn];
    pb0 = *(const uint4*)&b0row[kn];
    pb1 = *(const uint4*)&b0row[E * E + kn];
    pb2 = *(const uint4*)&b0row[2 * E * E + kn];

    bf16x8 ah = *(const bf16x8*)&Ah[(wave * 16 + l15) * LDA + quad * 8];
    bf16x8 al = *(const bf16x8*)&Al[(wave * 16 + l15) * LDA + quad * 8];
#pragma unroll
    for (int w = 0; w < 3; ++w)
#pragma unroll
      for (int nt = 0; nt < 4; ++nt) {
        bf16x8 bf = *(const bf16x8*)&Bs[w * 64 * LDA + (nt * 16 + l15) * LDA +
                                        quad * 8];
        acc[w][nt] =
            __builtin_amdgcn_mfma_f32_16x16x32_bf16(ah, bf, acc[w][nt], 0, 0, 0);
        acc[w][nt] =
            __builtin_amdgcn_mfma_f32_16x16x32_bf16(al, bf, acc[w][nt], 0, 0, 0);
      }
  }

  const int b = m0 >> 12;
  const int s_base = m0 & (SEQ - 1);
  const float QSCALE = 0.125f * 1.44269504f;  // fold 1/sqrt(D)*log2(e) into q

#pragma unroll
  for (int w = 0; w < 2; ++w) {
    ushort* dst = (w == 0) ? qg : kg;
    float sc = (w == 0) ? QSCALE : 1.0f;
#pragma unroll
    for (int nt = 0; nt < 4; ++nt)
#pragma unroll
      for (int r = 0; r < 4; ++r) {
        float v = acc[w][nt][r] * sc;
        float vo = __shfl_xor(v, 1);
        if (!(lane & 1)) {
          int s = s_base + wave * 16 + quad * 4 + r;
          size_t ix = ((size_t)(b * H + head) * SEQ + s) * D + nt * 16 + l15;
          *(unsigned*)&dst[ix] = pk_bf16(v, vo);
        }
      }
  }

  __syncthreads();  // Bs frag reads done in all waves before reuse
#pragma unroll
  for (int nt = 0; nt < 4; ++nt) {
    uint2 w2;
    w2.x = pk_bf16(acc[2][nt][0], acc[2][nt][1]);
    w2.y = pk_bf16(acc[2][nt][2], acc[2][nt][3]);
    *(uint2*)&vt_tile[(nt * 16 + l15) * 72 + wave * 16 + quad * 4] = w2;
  }
  __syncthreads();
  {
    int vr = tid >> 2, vs = (tid & 3) * 16;
    uint4 c0 = *(const uint4*)&vt_tile[vr * 72 + vs];
    uint4 c1 = *(const uint4*)&vt_tile[vr * 72 + vs + 8];
    size_t vo = ((size_t)(b * H + head) * D + vr) * SEQ + s_base + vs;
    *(uint4*)&vtg[vo] = c0;
    *(uint4*)&vtg[vo + 8] = c1;
  }
}

// ---------------------------------------------------------------------------
// Kernel 3: flash attention, 32x32x16 MFMA, swapped QK^T, P in registers.
// NEW this round: each wave owns TWO 32-row q-subtiles (64 q-rows) so every
// K/V fragment read from LDS feeds 2 MFMAs instead of 1 (frag-read
// duplication was the bottleneck: 160KB LDS/block-it vs 512cyc MFMA).
// Block = 4 waves (2 k-groups x 2 waves), 256 threads; grid unchanged.
//
// Layouts (verified mappings, guide §3):
//   C 32x32: col = lane&31, row = (reg&3) + 8*(reg>>2) + 4*(lane>>5)
//   A 32x32x16: lane holds A[row=lane&31][c=(lane>>5)*8 + j], j=0..7
//   B 32x32x16: lane holds B[c=(lane>>5)*8 + j][col=lane&31]
// ---------------------------------------------------------------------------
#define LDK 72  // padded stride (bf16): 144B, 16B-aligned

__global__ __launch_bounds__(256, 2) void attn_mfma(
    const ushort* __restrict__ qg, const ushort* __restrict__ kg,
    const ushort* __restrict__ vtg, float* __restrict__ out) {
  __shared__ ushort sm[4 * 64 * LDK + 256];  // Ks[2] | Vs[2] | lex
  ushort* Ks0 = sm;
  ushort* Vs0 = sm + 2 * 64 * LDK;
  float* lex = (float*)(sm + 4 * 64 * LDK);  // 128 floats

  const int qt = blockIdx.x;  // 0..31 (128 q-rows each)
  const int bh = blockIdx.y;
  const int tid = threadIdx.x;
  const int wave = tid >> 6;  // 0..3
  const int grp = wave >> 1, wq = wave & 1;
  const int lane = tid & 63;
  const int l31 = lane & 31, hi = lane >> 5;
  const int gtid = tid & 127;  // tid within group

  const ushort* qp = qg + (size_t)bh * SEQ * D;
  const ushort* kp = kg + (size_t)bh * SEQ * D;
  const ushort* vp = vtg + (size_t)bh * D * SEQ;
  ushort* Ksg = Ks0 + grp * 64 * LDK;
  ushort* Vsg = Vs0 + grp * 64 * LDK;

  const int qrow0 = qt * 128 + wq * 64;
  // Q as B-operand: qf[sub][ds] lane holds Q[qrow0+sub*32+l31][ds*16+hi*8+j]
  bf16x8 qf[2][4];
#pragma unroll
  for (int sub = 0; sub < 2; ++sub)
#pragma unroll
    for (int ds = 0; ds < 4; ++ds)
      qf[sub][ds] = *(const bf16x8*)&qp[(size_t)(qrow0 + sub * 32 + l31) * D +
                                        ds * 16 + hi * 8];

  f32x16 o[2][2];  // [sub][nt]
#pragma unroll
  for (int sub = 0; sub < 2; ++sub) {
    o[sub][0] = 0.f;
    o[sub][1] = 0.f;
  }
  float l_r[2] = {0.f, 0.f};  // per-lane row-sum, q = qrow0 + sub*32 + l31

  // staging: 128 threads/group cover 64x64 tile: 4 rows x 8 col-chunks each
  const int r0 = gtid >> 3, c0 = (gtid & 7) * 8;  // r0 in 0..15

  // preload tile it=0 (kt = grp)
  uint4 pk[4], pvv4[4];
#pragma unroll
  for (int u = 0; u < 4; ++u) {
    pk[u] = *(const uint4*)&kp[(size_t)(grp * 64 + r0 + u * 16) * D + c0];
    pvv4[u] = *(const uint4*)&vp[(size_t)(r0 + u * 16) * SEQ + grp * 64 + c0];
  }

  for (int it = 0; it < SEQ / 128; ++it) {
    __syncthreads();  // prev iter's frag reads done (both groups)
#pragma unroll
    for (int u = 0; u < 4; ++u) {
      *(uint4*)&Ksg[(r0 + u * 16) * LDK + c0] = pk[u];
      *(uint4*)&Vsg[(r0 + u * 16) * LDK + c0] = pvv4[u];
    }
    __syncthreads();

    // issue NEXT tile's loads; latency hides under this tile's compute
    {
      const int itn = (it + 1 < SEQ / 128) ? it + 1 : it;
      const int ktn = itn * 2 + grp;
#pragma unroll
      for (int u = 0; u < 4; ++u) {
        pk[u] =
            *(const uint4*)&kp[(size_t)(ktn * 64 + r0 + u * 16) * D + c0];
        pvv4[u] =
            *(const uint4*)&vp[(size_t)(r0 + u * 16) * SEQ + ktn * 64 + c0];
      }
    }

#pragma unroll
    for (int t = 0; t < 2; ++t) {  // two 32-k tiles per 64-k group tile
      // S^T = K·Q^T (32x32) for both q-subtiles; kf read once, used twice
      f32x16 st[2];
      st[0] = 0.f;
      st[1] = 0.f;
      __builtin_amdgcn_s_setprio(1);
#pragma unroll
      for (int ds = 0; ds < 4; ++ds) {
        bf16x8 kf =
            *(const bf16x8*)&Ksg[(t * 32 + l31) * LDK + ds * 16 + hi * 8];
        st[0] =
            __builtin_amdgcn_mfma_f32_32x32x16_bf16(kf, qf[0][ds], st[0], 0, 0, 0);
        st[1] =
            __builtin_amdgcn_mfma_f32_32x32x16_bf16(kf, qf[1][ds], st[1], 0, 0, 0);
      }
      __builtin_amdgcn_s_setprio(0);

      // max-free softmax + in-register P-frag build, per subtile
      bf16x8 pfA[2], pfB[2];
#pragma unroll
      for (int sub = 0; sub < 2; ++sub) {
        float pv[16];
#pragma unroll
        for (int r = 0; r < 16; ++r) pv[r] = fexp2(st[sub][r]);
        {
          float s01 = (pv[0] + pv[1]) + (pv[2] + pv[3]);
          float s23 = (pv[4] + pv[5]) + (pv[6] + pv[7]);
          float s45 = (pv[8] + pv[9]) + (pv[10] + pv[11]);
          float s67 = (pv[12] + pv[13]) + (pv[14] + pv[15]);
          l_r[sub] += (s01 + s23) + (s45 + s67);
        }
        unsigned w0[4], w1[4];
#pragma unroll
        for (int j = 0; j < 2; ++j) {
          {  // k-slice 0 (cols t*32 .. t*32+15)
            unsigned c0w = pk_bf16(pv[2 * j + 0], pv[2 * j + 1]);
            unsigned c1w = pk_bf16(pv[2 * j + 4], pv[2 * j + 5]);
            permswap32(c0w, c1w);
            w0[j] = c0w;
            w0[2 + j] = c1w;
          }
          {  // k-slice 1 (cols t*32+16 .. t*32+31)
            unsigned c0w = pk_bf16(pv[2 * j + 8], pv[2 * j + 9]);
            unsigned c1w = pk_bf16(pv[2 * j + 12], pv[2 * j + 13]);
            permswap32(c0w, c1w);
            w1[j] = c0w;
            w1[2 + j] = c1w;
          }
        }
        pfA[sub] =
            __builtin_bit_cast(bf16x8, (uint4v){w0[0], w0[1], w0[2], w0[3]});
        pfB[sub] =
            __builtin_bit_cast(bf16x8, (uint4v){w1[0], w1[1], w1[2], w1[3]});
      }

      // O += P·V; vf read once, used by both subtiles
      __builtin_amdgcn_s_setprio(1);
#pragma unroll
      for (int nt = 0; nt < 2; ++nt) {
        bf16x8 vf0 =
            *(const bf16x8*)&Vsg[(nt * 32 + l31) * LDK + t * 32 + hi * 8];
        bf16x8 vf1 = *(const bf16x8*)&Vsg[(nt * 32 + l31) * LDK + t * 32 + 16 +
                                          hi * 8];
        o[0][nt] = __builtin_amdgcn_mfma_f32_32x32x16_bf16(pfA[0], vf0,
                                                           o[0][nt], 0, 0, 0);
        o[0][nt] = __builtin_amdgcn_mfma_f32_32x32x16_bf16(pfB[0], vf1,
                                                           o[0][nt], 0, 0, 0);
        o[1][nt] = __builtin_amdgcn_mfma_f32_32x32x16_bf16(pfA[1], vf0,
                                                           o[1][nt], 0, 0, 0);
        o[1][nt] = __builtin_amdgcn_mfma_f32_32x32x16_bf16(pfB[1], vf1,
                                                           o[1][nt], 0, 0, 0);
      }
      __builtin_amdgcn_s_setprio(0);
    }
  }

  // ---- combine the two K-halves (additive: no max bookkeeping) ----
  __syncthreads();  // all waves done with Ks/Vs before Oex overlay
  float lg[2];
#pragma unroll
  for (int sub = 0; sub < 2; ++sub)
    lg[sub] = l_r[sub] + __shfl_xor(l_r[sub], 32);
  float* Oex = (float*)sm;  // [128 q][64 d], stride 68 floats
  if (grp == 1) {
#pragma unroll
    for (int sub = 0; sub < 2; ++sub)
#pragma unroll
      for (int nt = 0; nt < 2; ++nt)
#pragma unroll
        for (int r = 0; r < 16; ++r) {
          int row = (r & 3) + 8 * (r >> 2) + 4 * hi;
          Oex[(wq * 64 + sub * 32 + row) * 68 + nt * 32 + l31] = o[sub][nt][r];
        }
    if (lane < 32) {
      lex[wq * 64 + l31] = lg[0];
      lex[wq * 64 + 32 + l31] = lg[1];
    }
  }
  __syncthreads();
  if (grp == 0) {
    const int b = bh >> 3, h = bh & 7;
#pragma unroll
    for (int sub = 0; sub < 2; ++sub) {
      float linv = 1.f / (lg[sub] + lex[wq * 64 + sub * 32 + l31]);
#pragma unroll
      for (int r = 0; r < 16; ++r) {
        int row = (r & 3) + 8 * (r >> 2) + 4 * hi;
        float inv = __shfl(linv, row);  // lane `row` owns q = +row
        int srow = qt * 128 + wq * 64 + sub * 32 + row;
#pragma unroll
        for (int nt = 0; nt < 2; ++nt) {
          float val =
              o[sub][nt][r] + Oex[(wq * 64 + sub * 32 + row) * 68 + nt * 32 + l31];
          out[((size_t)b * SEQ + srow) * E + h * D + nt * 32 + l31] = val * inv;
        }
      }
    }
  }
}

// ---------------------------------------------------------------------------
extern "C" void kernel_launch(void* const* d_in, const int* in_sizes, int n_in,
                              void* d_out, int out_size, void* d_ws,
                              size_t ws_size, hipStream_t stream) {
  const float* rot = (const float*)d_in[0];
  const float* ent = (const float*)d_in[1];
  const float* x = (const float*)d_in[2];
  const float* wq = (const float*)d_in[3];
  const float* wk = (const float*)d_in[4];
  const float* wv = (const float*)d_in[5];
  float* out = (float*)d_out;

  const size_t NX = (size_t)BATCH * SEQ * E;  // 4M elements
  ushort* weffbT = (ushort*)d_ws;             // 3*E*E bf16 (1.5 MB)
  ushort* xh = weffbT + 3 * E * E;
  ushort* xl = xh + NX;
  ushort* qg = xl + NX;
  ushort* kg = qg + NX;
  ushort* vtg = kg + NX;

  xcast<<<dim3(NX / 1024), 256, 0, stream>>>(x, xh, xl);
  fold_tiled<<<dim3(E / 256, E / 8, 2), 256, 0, stream>>>(wq, wk, rot, ent,
                                                          weffbT);
  wv_cast<<<dim3(E * E / 1024), 256, 0, stream>>>(wv, weffbT + 2 * E * E);
  qkv_fused<<<dim3(H, BATCH * SEQ / 64), 256, 0, stream>>>(xh, xl, weffbT, qg,
                                                           kg, vtg);
  attn_mfma<<<dim3(SEQ / 128, BATCH * H), 256, 0, stream>>>(qg, kg, vtg, out);
}

// Round 3
// 251.575 us; speedup vs baseline: 1.3169x; 1.3169x over previous
//
#include <hip/hip_runtime.h>
#include <cstddef>

#define E 512
#define H 8
#define D 64
#define BATCH 2
#define SEQ 4096

typedef __attribute__((ext_vector_type(8))) short bf16x8;   // MFMA A/B frag
typedef __attribute__((ext_vector_type(4))) float f32x4;    // 16x16 C/D frag
typedef __attribute__((ext_vector_type(16))) float f32x16;  // 32x32 C/D frag
typedef __attribute__((ext_vector_type(4))) unsigned uint4v;

__device__ __forceinline__ ushort f2bf(float f) {
  unsigned u = __builtin_bit_cast(unsigned, f);
  u += 0x7fff + ((u >> 16) & 1);  // RNE
  return (ushort)(u >> 16);
}
__device__ __forceinline__ float bf2f(ushort h) {
  return __builtin_bit_cast(float, (unsigned)h << 16);
}
__device__ __forceinline__ unsigned pk_bf16(float lo, float hi) {
#if __has_builtin(__builtin_amdgcn_cvt_pk_bf16_f32)
  typedef __attribute__((ext_vector_type(2))) __bf16 bfv2;
  bfv2 r = __builtin_amdgcn_cvt_pk_bf16_f32(lo, hi);
  return __builtin_bit_cast(unsigned, r);
#else
  return (unsigned)f2bf(lo) | ((unsigned)f2bf(hi) << 16);
#endif
}
__device__ __forceinline__ float fexp2(float x) {
#if __has_builtin(__builtin_amdgcn_exp2f)
  return __builtin_amdgcn_exp2f(x);
#else
  return exp2f(x);
#endif
}
// lanes[32:63] of a  <->  lanes[0:31] of b
__device__ __forceinline__ void permswap32(unsigned& a, unsigned& b) {
  asm volatile("v_permlane32_swap_b32 %0, %1" : "+v"(a), "+v"(b));
}

// ---------------------------------------------------------------------------
// Kernel 0: cast x -> bf16 hi/lo split (xh + xl ~= x to ~16 mantissa bits)
// ---------------------------------------------------------------------------
__global__ __launch_bounds__(256) void xcast(const float* __restrict__ x,
                                             ushort* __restrict__ xh,
                                             ushort* __restrict__ xl) {
  size_t i = ((size_t)blockIdx.x * 256 + threadIdx.x) * 4;
  float4 v = *(const float4*)&x[i];
  ushort4 h, l;
  h.x = f2bf(v.x); l.x = f2bf(v.x - bf2f(h.x));
  h.y = f2bf(v.y); l.y = f2bf(v.y - bf2f(h.y));
  h.z = f2bf(v.z); l.z = f2bf(v.z - bf2f(h.z));
  h.w = f2bf(v.w); l.w = f2bf(v.w - bf2f(h.w));
  *(ushort4*)&xh[i] = h;
  *(ushort4*)&xl[i] = l;
}

// ---------------------------------------------------------------------------
// Kernel 1a: fold weights. Block = 256 k-lanes x 8 n (8 fp32 accs).
// ---------------------------------------------------------------------------
__global__ __launch_bounds__(256) void fold_tiled(
    const float* __restrict__ wq, const float* __restrict__ wk,
    const float* __restrict__ rot, const float* __restrict__ ent,
    ushort* __restrict__ weffbT) {
  const int which = blockIdx.z;
  const float* w = which ? wk : wq;
  const float* r = which ? ent : rot;
  const int k = blockIdx.x * 256 + threadIdx.x;
  const int n0 = blockIdx.y * 8;
  float acc[8] = {};
  for (int j0 = 0; j0 < E; j0 += 16) {
    float wv_[16];
#pragma unroll
    for (int u = 0; u < 16; ++u) wv_[u] = w[(size_t)(j0 + u) * E + k];
#pragma unroll
    for (int u = 0; u < 16; ++u)
#pragma unroll
      for (int t = 0; t < 8; ++t)
        acc[t] += wv_[u] * r[(size_t)(j0 + u) * E + n0 + t];
  }
#pragma unroll
  for (int t = 0; t < 8; ++t)
    weffbT[(size_t)which * E * E + (size_t)(n0 + t) * E + k] = f2bf(acc[t]);
}

// Kernel 1b: weffT[2][n][k] = bf16(wv[n][k]) — identity layout, pure cast.
__global__ __launch_bounds__(256) void wv_cast(const float* __restrict__ wv,
                                               ushort* __restrict__ dst) {
  size_t i = ((size_t)blockIdx.x * 256 + threadIdx.x) * 4;
  float4 v = *(const float4*)&wv[i];
  ushort4 o;
  o.x = f2bf(v.x); o.y = f2bf(v.y); o.z = f2bf(v.z); o.w = f2bf(v.w);
  *(ushort4*)&dst[i] = o;
}

// ---------------------------------------------------------------------------
// Kernel 2: fused QKV GEMM (unchanged; software-pipelined staging).
// ---------------------------------------------------------------------------
#define LDA 40  // padded LDS stride (bf16): 80B

__global__ __launch_bounds__(256) void qkv_fused(
    const ushort* __restrict__ xhg, const ushort* __restrict__ xlg,
    const ushort* __restrict__ weffbT, ushort* __restrict__ qg,
    ushort* __restrict__ kg, ushort* __restrict__ vtg) {
  __shared__ ushort sm[5 * 64 * LDA];  // Ah | Al | B0 | B1 | B2
  ushort* Ah = sm;
  ushort* Al = sm + 64 * LDA;
  ushort* Bs = sm + 2 * 64 * LDA;
  ushort* vt_tile = Bs;  // epilogue reuse: 64*72 <= 3*64*40

  const int head = blockIdx.x;
  const int m0 = blockIdx.y * 64;
  const int tid = threadIdx.x;
  const int wave = tid >> 6, lane = tid & 63;
  const int l15 = lane & 15, quad = lane >> 4;
  const int ar = tid >> 2, ac8 = (tid & 3) * 8;  // 64x32 tile staging slot

  const ushort* arow = xhg + (size_t)(m0 + ar) * E + ac8;
  const ushort* lrow = xlg + (size_t)(m0 + ar) * E + ac8;
  const ushort* b0row = weffbT + (size_t)(head * 64 + ar) * E + ac8;

  f32x4 acc[3][4];
#pragma unroll
  for (int w = 0; w < 3; ++w)
#pragma unroll
    for (int nt = 0; nt < 4; ++nt) acc[w][nt] = (f32x4){0.f, 0.f, 0.f, 0.f};

  // preload tile k0=0
  uint4 pa_h = *(const uint4*)&arow[0];
  uint4 pa_l = *(const uint4*)&lrow[0];
  uint4 pb0 = *(const uint4*)&b0row[0];
  uint4 pb1 = *(const uint4*)&b0row[E * E];
  uint4 pb2 = *(const uint4*)&b0row[2 * E * E];

  for (int k0 = 0; k0 < E; k0 += 32) {
    __syncthreads();
    *(uint4*)&Ah[ar * LDA + ac8] = pa_h;
    *(uint4*)&Al[ar * LDA + ac8] = pa_l;
    *(uint4*)&Bs[0 * 64 * LDA + ar * LDA + ac8] = pb0;
    *(uint4*)&Bs[1 * 64 * LDA + ar * LDA + ac8] = pb1;
    *(uint4*)&Bs[2 * 64 * LDA + ar * LDA + ac8] = pb2;
    __syncthreads();

    const int kn = (k0 + 32 < E) ? k0 + 32 : 0;
    pa_h = *(const uint4*)&arow[kn];
    pa_l = *(const uint4*)&lrow[kn];
    pb0 = *(const uint4*)&b0row[kn];
    pb1 = *(const uint4*)&b0row[E * E + kn];
    pb2 = *(const uint4*)&b0row[2 * E * E + kn];

    bf16x8 ah = *(const bf16x8*)&Ah[(wave * 16 + l15) * LDA + quad * 8];
    bf16x8 al = *(const bf16x8*)&Al[(wave * 16 + l15) * LDA + quad * 8];
#pragma unroll
    for (int w = 0; w < 3; ++w)
#pragma unroll
      for (int nt = 0; nt < 4; ++nt) {
        bf16x8 bf = *(const bf16x8*)&Bs[w * 64 * LDA + (nt * 16 + l15) * LDA +
                                        quad * 8];
        acc[w][nt] =
            __builtin_amdgcn_mfma_f32_16x16x32_bf16(ah, bf, acc[w][nt], 0, 0, 0);
        acc[w][nt] =
            __builtin_amdgcn_mfma_f32_16x16x32_bf16(al, bf, acc[w][nt], 0, 0, 0);
      }
  }

  const int b = m0 >> 12;
  const int s_base = m0 & (SEQ - 1);
  const float QSCALE = 0.125f * 1.44269504f;  // fold 1/sqrt(D)*log2(e) into q

#pragma unroll
  for (int w = 0; w < 2; ++w) {
    ushort* dst = (w == 0) ? qg : kg;
    float sc = (w == 0) ? QSCALE : 1.0f;
#pragma unroll
    for (int nt = 0; nt < 4; ++nt)
#pragma unroll
      for (int r = 0; r < 4; ++r) {
        float v = acc[w][nt][r] * sc;
        float vo = __shfl_xor(v, 1);
        if (!(lane & 1)) {
          int s = s_base + wave * 16 + quad * 4 + r;
          size_t ix = ((size_t)(b * H + head) * SEQ + s) * D + nt * 16 + l15;
          *(unsigned*)&dst[ix] = pk_bf16(v, vo);
        }
      }
  }

  __syncthreads();  // Bs frag reads done in all waves before reuse
#pragma unroll
  for (int nt = 0; nt < 4; ++nt) {
    uint2 w2;
    w2.x = pk_bf16(acc[2][nt][0], acc[2][nt][1]);
    w2.y = pk_bf16(acc[2][nt][2], acc[2][nt][3]);
    *(uint2*)&vt_tile[(nt * 16 + l15) * 72 + wave * 16 + quad * 4] = w2;
  }
  __syncthreads();
  {
    int vr = tid >> 2, vs = (tid & 3) * 16;
    uint4 c0 = *(const uint4*)&vt_tile[vr * 72 + vs];
    uint4 c1 = *(const uint4*)&vt_tile[vr * 72 + vs + 8];
    size_t vo = ((size_t)(b * H + head) * D + vr) * SEQ + s_base + vs;
    *(uint4*)&vtg[vo] = c0;
    *(uint4*)&vtg[vo + 8] = c1;
  }
}

// ---------------------------------------------------------------------------
// Kernel 3: flash attention, 32x32x16 MFMA, swapped QK^T, P in registers
// (round-1 per-wave math, verified). NEW this round: NO in-block K-split —
// block = 4 waves / 256 threads sharing ONE 64-key staged tile, 64 iters.
// Wins: LDS 37KB -> 18KB (more blocks/CU), 4-wave barriers (less lockstep),
// combine epilogue (Oex/lex LDS round-trip) deleted: shfl_xor(l_r,32)
// already totals the row-sum since lanes l/l+32 cover complementary k-rows.
//
// Layouts (verified mappings, guide §3):
//   C 32x32: col = lane&31, row = (reg&3) + 8*(reg>>2) + 4*(lane>>5)
//   A 32x32x16: lane holds A[row=lane&31][c=(lane>>5)*8 + j], j=0..7
//   B 32x32x16: lane holds B[c=(lane>>5)*8 + j][col=lane&31]
// ---------------------------------------------------------------------------
#define LDK 72  // padded stride (bf16): 144B, 16B-aligned

__global__ __launch_bounds__(256, 4) void attn_mfma(
    const ushort* __restrict__ qg, const ushort* __restrict__ kg,
    const ushort* __restrict__ vtg, float* __restrict__ out) {
  __shared__ ushort Ks[64 * LDK];  // K tile [kcol][d]
  __shared__ ushort Vs[64 * LDK];  // Vt tile [d][kcol]

  const int qt = blockIdx.x;  // 0..31 (128 q-rows each)
  const int bh = blockIdx.y;
  const int tid = threadIdx.x;
  const int wave = tid >> 6;  // 0..3
  const int lane = tid & 63;
  const int l31 = lane & 31, hi = lane >> 5;

  const ushort* qp = qg + (size_t)bh * SEQ * D;
  const ushort* kp = kg + (size_t)bh * SEQ * D;
  const ushort* vp = vtg + (size_t)bh * D * SEQ;

  const int qrow0 = qt * 128 + wave * 32;
  // Q as B-operand: qf[ds] lane holds Q[qrow0+l31][ds*16 + hi*8 + j]
  bf16x8 qf[4];
#pragma unroll
  for (int ds = 0; ds < 4; ++ds)
    qf[ds] =
        *(const bf16x8*)&qp[(size_t)(qrow0 + l31) * D + ds * 16 + hi * 8];

  f32x16 o[2];
  o[0] = 0.f;
  o[1] = 0.f;
  float l_r = 0.f;  // per-lane partial row-sum for q = qrow0 + l31

  // staging: 256 threads cover 64x64 tiles: rows r0 and r0+32, 8-col chunk
  const int r0 = tid >> 3, c0 = (tid & 7) * 8;  // r0 in 0..31
  const int r1 = 32 + r0;

  // preload tile it=0
  uint4 pk0 = *(const uint4*)&kp[(size_t)r0 * D + c0];
  uint4 pk1 = *(const uint4*)&kp[(size_t)r1 * D + c0];
  uint4 pv0 = *(const uint4*)&vp[(size_t)r0 * SEQ + c0];
  uint4 pv1 = *(const uint4*)&vp[(size_t)r1 * SEQ + c0];

  for (int it = 0; it < SEQ / 64; ++it) {
    __syncthreads();  // prev iter's frag reads done
    *(uint4*)&Ks[r0 * LDK + c0] = pk0;
    *(uint4*)&Ks[r1 * LDK + c0] = pk1;
    *(uint4*)&Vs[r0 * LDK + c0] = pv0;
    *(uint4*)&Vs[r1 * LDK + c0] = pv1;
    __syncthreads();

    // issue NEXT tile's loads; latency hides under this tile's compute
    {
      const int itn = (it + 1 < SEQ / 64) ? it + 1 : it;
      const ushort* ksrc = kp + (size_t)itn * 64 * D;
      pk0 = *(const uint4*)&ksrc[r0 * D + c0];
      pk1 = *(const uint4*)&ksrc[r1 * D + c0];
      pv0 = *(const uint4*)&vp[(size_t)r0 * SEQ + itn * 64 + c0];
      pv1 = *(const uint4*)&vp[(size_t)r1 * SEQ + itn * 64 + c0];
    }

#pragma unroll
    for (int t = 0; t < 2; ++t) {  // two 32-k subtiles per staged 64-k tile
      // S^T tile = K·Q^T (32x32), accumulate over d
      f32x16 st = 0.f;
      __builtin_amdgcn_s_setprio(1);
#pragma unroll
      for (int ds = 0; ds < 4; ++ds) {
        bf16x8 kf =
            *(const bf16x8*)&Ks[(t * 32 + l31) * LDK + ds * 16 + hi * 8];
        st = __builtin_amdgcn_mfma_f32_32x32x16_bf16(kf, qf[ds], st, 0, 0, 0);
      }
      __builtin_amdgcn_s_setprio(0);

      // max-free softmax: p = exp2(score), pairwise row-sum
      float pv[16];
#pragma unroll
      for (int r = 0; r < 16; ++r) pv[r] = fexp2(st[r]);
      {
        float s01 = (pv[0] + pv[1]) + (pv[2] + pv[3]);
        float s23 = (pv[4] + pv[5]) + (pv[6] + pv[7]);
        float s45 = (pv[8] + pv[9]) + (pv[10] + pv[11]);
        float s67 = (pv[12] + pv[13]) + (pv[14] + pv[15]);
        l_r += (s01 + s23) + (s45 + s67);
      }

      // build PV A-frags in-register: per (s,j): pack the tau=0 and tau=1
      // words, swap halves -> word j (src half 0) and word 2+j (src half 1)
      unsigned w0[4], w1[4];
#pragma unroll
      for (int j = 0; j < 2; ++j) {
        {  // k-slice 0 (cols t*32 .. t*32+15)
          unsigned c0w = pk_bf16(pv[2 * j + 0], pv[2 * j + 1]);
          unsigned c1w = pk_bf16(pv[2 * j + 4], pv[2 * j + 5]);
          permswap32(c0w, c1w);
          w0[j] = c0w;
          w0[2 + j] = c1w;
        }
        {  // k-slice 1 (cols t*32+16 .. t*32+31)
          unsigned c0w = pk_bf16(pv[2 * j + 8], pv[2 * j + 9]);
          unsigned c1w = pk_bf16(pv[2 * j + 12], pv[2 * j + 13]);
          permswap32(c0w, c1w);
          w1[j] = c0w;
          w1[2 + j] = c1w;
        }
      }
      bf16x8 pf0 =
          __builtin_bit_cast(bf16x8, (uint4v){w0[0], w0[1], w0[2], w0[3]});
      bf16x8 pf1 =
          __builtin_bit_cast(bf16x8, (uint4v){w1[0], w1[1], w1[2], w1[3]});

      // O += P·V over this 32-k subtile (two 16-k steps), both 32-d halves
      __builtin_amdgcn_s_setprio(1);
#pragma unroll
      for (int nt = 0; nt < 2; ++nt) {
        bf16x8 vf0 =
            *(const bf16x8*)&Vs[(nt * 32 + l31) * LDK + t * 32 + hi * 8];
        o[nt] = __builtin_amdgcn_mfma_f32_32x32x16_bf16(pf0, vf0, o[nt], 0, 0,
                                                        0);
        bf16x8 vf1 = *(const bf16x8*)&Vs[(nt * 32 + l31) * LDK + t * 32 + 16 +
                                         hi * 8];
        o[nt] = __builtin_amdgcn_mfma_f32_32x32x16_bf16(pf1, vf1, o[nt], 0, 0,
                                                        0);
      }
      __builtin_amdgcn_s_setprio(0);
    }
  }

  // ---- epilogue: row-sum is complete per lane-pair; scale and store ----
  float lg = l_r + __shfl_xor(l_r, 32);  // lanes l/l+32 cover all k-rows
  float linv = 1.f / lg;
  const int b = bh >> 3, h = bh & 7;
#pragma unroll
  for (int r = 0; r < 16; ++r) {
    int row = (r & 3) + 8 * (r >> 2) + 4 * hi;
    float inv = __shfl(linv, row);  // lane `row` owns q = qrow0 + row
    int srow = qt * 128 + wave * 32 + row;
#pragma unroll
    for (int nt = 0; nt < 2; ++nt) {
      out[((size_t)b * SEQ + srow) * E + h * D + nt * 32 + l31] =
          o[nt][r] * inv;
    }
  }
}

// ---------------------------------------------------------------------------
extern "C" void kernel_launch(void* const* d_in, const int* in_sizes, int n_in,
                              void* d_out, int out_size, void* d_ws,
                              size_t ws_size, hipStream_t stream) {
  const float* rot = (const float*)d_in[0];
  const float* ent = (const float*)d_in[1];
  const float* x = (const float*)d_in[2];
  const float* wq = (const float*)d_in[3];
  const float* wk = (const float*)d_in[4];
  const float* wv = (const float*)d_in[5];
  float* out = (float*)d_out;

  const size_t NX = (size_t)BATCH * SEQ * E;  // 4M elements
  ushort* weffbT = (ushort*)d_ws;             // 3*E*E bf16 (1.5 MB)
  ushort* xh = weffbT + 3 * E * E;
  ushort* xl = xh + NX;
  ushort* qg = xl + NX;
  ushort* kg = qg + NX;
  ushort* vtg = kg + NX;

  xcast<<<dim3(NX / 1024), 256, 0, stream>>>(x, xh, xl);
  fold_tiled<<<dim3(E / 256, E / 8, 2), 256, 0, stream>>>(wq, wk, rot, ent,
                                                          weffbT);
  wv_cast<<<dim3(E * E / 1024), 256, 0, stream>>>(wv, weffbT + 2 * E * E);
  qkv_fused<<<dim3(H, BATCH * SEQ / 64), 256, 0, stream>>>(xh, xl, weffbT, qg,
                                                           kg, vtg);
  attn_mfma<<<dim3(SEQ / 128, BATCH * H), 256, 0, stream>>>(qg, kg, vtg, out);
}

// Round 4
// 246.582 us; speedup vs baseline: 1.3436x; 1.0202x over previous
//
#include <hip/hip_runtime.h>
#include <cstddef>

#define E 512
#define H 8
#define D 64
#define BATCH 2
#define SEQ 4096

typedef __attribute__((ext_vector_type(8))) short bf16x8;   // MFMA A/B frag
typedef __attribute__((ext_vector_type(4))) float f32x4;    // 16x16 C/D frag
typedef __attribute__((ext_vector_type(16))) float f32x16;  // 32x32 C/D frag
typedef __attribute__((ext_vector_type(4))) unsigned uint4v;

__device__ __forceinline__ ushort f2bf(float f) {
  unsigned u = __builtin_bit_cast(unsigned, f);
  u += 0x7fff + ((u >> 16) & 1);  // RNE
  return (ushort)(u >> 16);
}
__device__ __forceinline__ float bf2f(ushort h) {
  return __builtin_bit_cast(float, (unsigned)h << 16);
}
__device__ __forceinline__ unsigned pk_bf16(float lo, float hi) {
#if __has_builtin(__builtin_amdgcn_cvt_pk_bf16_f32)
  typedef __attribute__((ext_vector_type(2))) __bf16 bfv2;
  bfv2 r = __builtin_amdgcn_cvt_pk_bf16_f32(lo, hi);
  return __builtin_bit_cast(unsigned, r);
#else
  return (unsigned)f2bf(lo) | ((unsigned)f2bf(hi) << 16);
#endif
}
__device__ __forceinline__ float fexp2(float x) {
#if __has_builtin(__builtin_amdgcn_exp2f)
  return __builtin_amdgcn_exp2f(x);
#else
  return exp2f(x);
#endif
}
// lanes[32:63] of a  <->  lanes[0:31] of b. NON-volatile: scheduler may
// move it (we want softmax(t1) to slide under PV(t0) MFMAs).
__device__ __forceinline__ void permswap32(unsigned& a, unsigned& b) {
  asm("v_permlane32_swap_b32 %0, %1" : "+v"(a), "+v"(b));
}

// ---------------------------------------------------------------------------
// Kernel 0: cast x -> bf16 hi/lo split (xh + xl ~= x to ~16 mantissa bits)
// ---------------------------------------------------------------------------
__global__ __launch_bounds__(256) void xcast(const float* __restrict__ x,
                                             ushort* __restrict__ xh,
                                             ushort* __restrict__ xl) {
  size_t i = ((size_t)blockIdx.x * 256 + threadIdx.x) * 4;
  float4 v = *(const float4*)&x[i];
  ushort4 h, l;
  h.x = f2bf(v.x); l.x = f2bf(v.x - bf2f(h.x));
  h.y = f2bf(v.y); l.y = f2bf(v.y - bf2f(h.y));
  h.z = f2bf(v.z); l.z = f2bf(v.z - bf2f(h.z));
  h.w = f2bf(v.w); l.w = f2bf(v.w - bf2f(h.w));
  *(ushort4*)&xh[i] = h;
  *(ushort4*)&xl[i] = l;
}

// ---------------------------------------------------------------------------
// Kernel 1a: fold weights. Block = 256 k-lanes x 8 n (8 fp32 accs).
// ---------------------------------------------------------------------------
__global__ __launch_bounds__(256) void fold_tiled(
    const float* __restrict__ wq, const float* __restrict__ wk,
    const float* __restrict__ rot, const float* __restrict__ ent,
    ushort* __restrict__ weffbT) {
  const int which = blockIdx.z;
  const float* w = which ? wk : wq;
  const float* r = which ? ent : rot;
  const int k = blockIdx.x * 256 + threadIdx.x;
  const int n0 = blockIdx.y * 8;
  float acc[8] = {};
  for (int j0 = 0; j0 < E; j0 += 16) {
    float wv_[16];
#pragma unroll
    for (int u = 0; u < 16; ++u) wv_[u] = w[(size_t)(j0 + u) * E + k];
#pragma unroll
    for (int u = 0; u < 16; ++u)
#pragma unroll
      for (int t = 0; t < 8; ++t)
        acc[t] += wv_[u] * r[(size_t)(j0 + u) * E + n0 + t];
  }
#pragma unroll
  for (int t = 0; t < 8; ++t)
    weffbT[(size_t)which * E * E + (size_t)(n0 + t) * E + k] = f2bf(acc[t]);
}

// Kernel 1b: weffT[2][n][k] = bf16(wv[n][k]) — identity layout, pure cast.
__global__ __launch_bounds__(256) void wv_cast(const float* __restrict__ wv,
                                               ushort* __restrict__ dst) {
  size_t i = ((size_t)blockIdx.x * 256 + threadIdx.x) * 4;
  float4 v = *(const float4*)&wv[i];
  ushort4 o;
  o.x = f2bf(v.x); o.y = f2bf(v.y); o.z = f2bf(v.z); o.w = f2bf(v.w);
  *(ushort4*)&dst[i] = o;
}

// ---------------------------------------------------------------------------
// Kernel 2: fused QKV GEMM (unchanged; software-pipelined staging).
// ---------------------------------------------------------------------------
#define LDA 40  // padded LDS stride (bf16): 80B

__global__ __launch_bounds__(256) void qkv_fused(
    const ushort* __restrict__ xhg, const ushort* __restrict__ xlg,
    const ushort* __restrict__ weffbT, ushort* __restrict__ qg,
    ushort* __restrict__ kg, ushort* __restrict__ vtg) {
  __shared__ ushort sm[5 * 64 * LDA];  // Ah | Al | B0 | B1 | B2
  ushort* Ah = sm;
  ushort* Al = sm + 64 * LDA;
  ushort* Bs = sm + 2 * 64 * LDA;
  ushort* vt_tile = Bs;  // epilogue reuse: 64*72 <= 3*64*40

  const int head = blockIdx.x;
  const int m0 = blockIdx.y * 64;
  const int tid = threadIdx.x;
  const int wave = tid >> 6, lane = tid & 63;
  const int l15 = lane & 15, quad = lane >> 4;
  const int ar = tid >> 2, ac8 = (tid & 3) * 8;  // 64x32 tile staging slot

  const ushort* arow = xhg + (size_t)(m0 + ar) * E + ac8;
  const ushort* lrow = xlg + (size_t)(m0 + ar) * E + ac8;
  const ushort* b0row = weffbT + (size_t)(head * 64 + ar) * E + ac8;

  f32x4 acc[3][4];
#pragma unroll
  for (int w = 0; w < 3; ++w)
#pragma unroll
    for (int nt = 0; nt < 4; ++nt) acc[w][nt] = (f32x4){0.f, 0.f, 0.f, 0.f};

  // preload tile k0=0
  uint4 pa_h = *(const uint4*)&arow[0];
  uint4 pa_l = *(const uint4*)&lrow[0];
  uint4 pb0 = *(const uint4*)&b0row[0];
  uint4 pb1 = *(const uint4*)&b0row[E * E];
  uint4 pb2 = *(const uint4*)&b0row[2 * E * E];

  for (int k0 = 0; k0 < E; k0 += 32) {
    __syncthreads();
    *(uint4*)&Ah[ar * LDA + ac8] = pa_h;
    *(uint4*)&Al[ar * LDA + ac8] = pa_l;
    *(uint4*)&Bs[0 * 64 * LDA + ar * LDA + ac8] = pb0;
    *(uint4*)&Bs[1 * 64 * LDA + ar * LDA + ac8] = pb1;
    *(uint4*)&Bs[2 * 64 * LDA + ar * LDA + ac8] = pb2;
    __syncthreads();

    const int kn = (k0 + 32 < E) ? k0 + 32 : 0;
    pa_h = *(const uint4*)&arow[kn];
    pa_l = *(const uint4*)&lrow[kn];
    pb0 = *(const uint4*)&b0row[kn];
    pb1 = *(const uint4*)&b0row[E * E + kn];
    pb2 = *(const uint4*)&b0row[2 * E * E + kn];

    bf16x8 ah = *(const bf16x8*)&Ah[(wave * 16 + l15) * LDA + quad * 8];
    bf16x8 al = *(const bf16x8*)&Al[(wave * 16 + l15) * LDA + quad * 8];
#pragma unroll
    for (int w = 0; w < 3; ++w)
#pragma unroll
      for (int nt = 0; nt < 4; ++nt) {
        bf16x8 bf = *(const bf16x8*)&Bs[w * 64 * LDA + (nt * 16 + l15) * LDA +
                                        quad * 8];
        acc[w][nt] =
            __builtin_amdgcn_mfma_f32_16x16x32_bf16(ah, bf, acc[w][nt], 0, 0, 0);
        acc[w][nt] =
            __builtin_amdgcn_mfma_f32_16x16x32_bf16(al, bf, acc[w][nt], 0, 0, 0);
      }
  }

  const int b = m0 >> 12;
  const int s_base = m0 & (SEQ - 1);
  const float QSCALE = 0.125f * 1.44269504f;  // fold 1/sqrt(D)*log2(e) into q

#pragma unroll
  for (int w = 0; w < 2; ++w) {
    ushort* dst = (w == 0) ? qg : kg;
    float sc = (w == 0) ? QSCALE : 1.0f;
#pragma unroll
    for (int nt = 0; nt < 4; ++nt)
#pragma unroll
      for (int r = 0; r < 4; ++r) {
        float v = acc[w][nt][r] * sc;
        float vo = __shfl_xor(v, 1);
        if (!(lane & 1)) {
          int s = s_base + wave * 16 + quad * 4 + r;
          size_t ix = ((size_t)(b * H + head) * SEQ + s) * D + nt * 16 + l15;
          *(unsigned*)&dst[ix] = pk_bf16(v, vo);
        }
      }
  }

  __syncthreads();  // Bs frag reads done in all waves before reuse
#pragma unroll
  for (int nt = 0; nt < 4; ++nt) {
    uint2 w2;
    w2.x = pk_bf16(acc[2][nt][0], acc[2][nt][1]);
    w2.y = pk_bf16(acc[2][nt][2], acc[2][nt][3]);
    *(uint2*)&vt_tile[(nt * 16 + l15) * 72 + wave * 16 + quad * 4] = w2;
  }
  __syncthreads();
  {
    int vr = tid >> 2, vs = (tid & 3) * 16;
    uint4 c0 = *(const uint4*)&vt_tile[vr * 72 + vs];
    uint4 c1 = *(const uint4*)&vt_tile[vr * 72 + vs + 8];
    size_t vo = ((size_t)(b * H + head) * D + vr) * SEQ + s_base + vs;
    *(uint4*)&vtg[vo] = c0;
    *(uint4*)&vtg[vo + 8] = c1;
  }
}

// ---------------------------------------------------------------------------
// Kernel 3: flash attention, 32x32x16 MFMA, swapped QK^T, P in registers.
// NEW this round: the two 32-k subtiles of each staged 64-key tile are
// software-pipelined INSIDE the wave: both QK chains issue interleaved
// (st0/st1 -> MFMA pipe fed by 2 independent chains), then
// sm(t0) -> PV(t0) -> sm(t1) -> PV(t1) in ONE setprio region with
// non-volatile permswap asm, so the scheduler can run sm(t1) VALU under
// PV(t0) MFMAs. Breaks the serial QK->exp->pack->PV chain that left
// MfmaUtil at 27% / VALUBusy at 47% for three rounds.
//
// Layouts (verified mappings, guide §3):
//   C 32x32: col = lane&31, row = (reg&3) + 8*(reg>>2) + 4*(lane>>5)
//   A 32x32x16: lane holds A[row=lane&31][c=(lane>>5)*8 + j], j=0..7
//   B 32x32x16: lane holds B[c=(lane>>5)*8 + j][col=lane&31]
// ---------------------------------------------------------------------------
#define LDK 72  // padded stride (bf16): 144B, 16B-aligned

__global__ __launch_bounds__(256, 2) void attn_mfma(
    const ushort* __restrict__ qg, const ushort* __restrict__ kg,
    const ushort* __restrict__ vtg, float* __restrict__ out) {
  __shared__ ushort Ks[64 * LDK];  // K tile [kcol][d]
  __shared__ ushort Vs[64 * LDK];  // Vt tile [d][kcol]

  const int qt = blockIdx.x;  // 0..31 (128 q-rows each)
  const int bh = blockIdx.y;
  const int tid = threadIdx.x;
  const int wave = tid >> 6;  // 0..3
  const int lane = tid & 63;
  const int l31 = lane & 31, hi = lane >> 5;

  const ushort* qp = qg + (size_t)bh * SEQ * D;
  const ushort* kp = kg + (size_t)bh * SEQ * D;
  const ushort* vp = vtg + (size_t)bh * D * SEQ;

  const int qrow0 = qt * 128 + wave * 32;
  // Q as B-operand: qf[ds] lane holds Q[qrow0+l31][ds*16 + hi*8 + j]
  bf16x8 qf[4];
#pragma unroll
  for (int ds = 0; ds < 4; ++ds)
    qf[ds] =
        *(const bf16x8*)&qp[(size_t)(qrow0 + l31) * D + ds * 16 + hi * 8];

  f32x16 o[2];
  o[0] = 0.f;
  o[1] = 0.f;
  float l_r = 0.f;  // per-lane partial row-sum for q = qrow0 + l31

  // staging: 256 threads cover 64x64 tiles: rows r0 and r0+32, 8-col chunk
  const int r0 = tid >> 3, c0 = (tid & 7) * 8;  // r0 in 0..31
  const int r1 = 32 + r0;

  // preload tile it=0
  uint4 pk0 = *(const uint4*)&kp[(size_t)r0 * D + c0];
  uint4 pk1 = *(const uint4*)&kp[(size_t)r1 * D + c0];
  uint4 pv0 = *(const uint4*)&vp[(size_t)r0 * SEQ + c0];
  uint4 pv1 = *(const uint4*)&vp[(size_t)r1 * SEQ + c0];

  for (int it = 0; it < SEQ / 64; ++it) {
    __syncthreads();  // prev iter's frag reads done
    *(uint4*)&Ks[r0 * LDK + c0] = pk0;
    *(uint4*)&Ks[r1 * LDK + c0] = pk1;
    *(uint4*)&Vs[r0 * LDK + c0] = pv0;
    *(uint4*)&Vs[r1 * LDK + c0] = pv1;
    __syncthreads();

    // issue NEXT tile's loads; latency hides under this tile's compute
    {
      const int itn = (it + 1 < SEQ / 64) ? it + 1 : it;
      const ushort* ksrc = kp + (size_t)itn * 64 * D;
      pk0 = *(const uint4*)&ksrc[r0 * D + c0];
      pk1 = *(const uint4*)&ksrc[r1 * D + c0];
      pv0 = *(const uint4*)&vp[(size_t)r0 * SEQ + itn * 64 + c0];
      pv1 = *(const uint4*)&vp[(size_t)r1 * SEQ + itn * 64 + c0];
    }

    __builtin_amdgcn_s_setprio(1);
    // ---- QK for BOTH subtiles, chains interleaved ----
    f32x16 st0 = 0.f, st1 = 0.f;
#pragma unroll
    for (int ds = 0; ds < 4; ++ds) {
      bf16x8 kf0 = *(const bf16x8*)&Ks[(l31)*LDK + ds * 16 + hi * 8];
      bf16x8 kf1 = *(const bf16x8*)&Ks[(32 + l31) * LDK + ds * 16 + hi * 8];
      st0 = __builtin_amdgcn_mfma_f32_32x32x16_bf16(kf0, qf[ds], st0, 0, 0, 0);
      st1 = __builtin_amdgcn_mfma_f32_32x32x16_bf16(kf1, qf[ds], st1, 0, 0, 0);
    }

    // ---- t = 0: softmax + P-frag build + PV ----
    bf16x8 pf00, pf01;
    {
      float pv[16];
#pragma unroll
      for (int r = 0; r < 16; ++r) pv[r] = fexp2(st0[r]);
      float s01 = (pv[0] + pv[1]) + (pv[2] + pv[3]);
      float s23 = (pv[4] + pv[5]) + (pv[6] + pv[7]);
      float s45 = (pv[8] + pv[9]) + (pv[10] + pv[11]);
      float s67 = (pv[12] + pv[13]) + (pv[14] + pv[15]);
      l_r += (s01 + s23) + (s45 + s67);
      unsigned w0[4], w1[4];
#pragma unroll
      for (int j = 0; j < 2; ++j) {
        {
          unsigned c0w = pk_bf16(pv[2 * j + 0], pv[2 * j + 1]);
          unsigned c1w = pk_bf16(pv[2 * j + 4], pv[2 * j + 5]);
          permswap32(c0w, c1w);
          w0[j] = c0w;
          w0[2 + j] = c1w;
        }
        {
          unsigned c0w = pk_bf16(pv[2 * j + 8], pv[2 * j + 9]);
          unsigned c1w = pk_bf16(pv[2 * j + 12], pv[2 * j + 13]);
          permswap32(c0w, c1w);
          w1[j] = c0w;
          w1[2 + j] = c1w;
        }
      }
      pf00 = __builtin_bit_cast(bf16x8, (uint4v){w0[0], w0[1], w0[2], w0[3]});
      pf01 = __builtin_bit_cast(bf16x8, (uint4v){w1[0], w1[1], w1[2], w1[3]});
    }
#pragma unroll
    for (int nt = 0; nt < 2; ++nt) {
      bf16x8 vf0 = *(const bf16x8*)&Vs[(nt * 32 + l31) * LDK + hi * 8];
      o[nt] =
          __builtin_amdgcn_mfma_f32_32x32x16_bf16(pf00, vf0, o[nt], 0, 0, 0);
      bf16x8 vf1 = *(const bf16x8*)&Vs[(nt * 32 + l31) * LDK + 16 + hi * 8];
      o[nt] =
          __builtin_amdgcn_mfma_f32_32x32x16_bf16(pf01, vf1, o[nt], 0, 0, 0);
    }

    // ---- t = 1: softmax (scheduler may overlap with PV(t0)) + PV ----
    bf16x8 pf10, pf11;
    {
      float pv[16];
#pragma unroll
      for (int r = 0; r < 16; ++r) pv[r] = fexp2(st1[r]);
      float s01 = (pv[0] + pv[1]) + (pv[2] + pv[3]);
      float s23 = (pv[4] + pv[5]) + (pv[6] + pv[7]);
      float s45 = (pv[8] + pv[9]) + (pv[10] + pv[11]);
      float s67 = (pv[12] + pv[13]) + (pv[14] + pv[15]);
      l_r += (s01 + s23) + (s45 + s67);
      unsigned w0[4], w1[4];
#pragma unroll
      for (int j = 0; j < 2; ++j) {
        {
          unsigned c0w = pk_bf16(pv[2 * j + 0], pv[2 * j + 1]);
          unsigned c1w = pk_bf16(pv[2 * j + 4], pv[2 * j + 5]);
          permswap32(c0w, c1w);
          w0[j] = c0w;
          w0[2 + j] = c1w;
        }
        {
          unsigned c0w = pk_bf16(pv[2 * j + 8], pv[2 * j + 9]);
          unsigned c1w = pk_bf16(pv[2 * j + 12], pv[2 * j + 13]);
          permswap32(c0w, c1w);
          w1[j] = c0w;
          w1[2 + j] = c1w;
        }
      }
      pf10 = __builtin_bit_cast(bf16x8, (uint4v){w0[0], w0[1], w0[2], w0[3]});
      pf11 = __builtin_bit_cast(bf16x8, (uint4v){w1[0], w1[1], w1[2], w1[3]});
    }
#pragma unroll
    for (int nt = 0; nt < 2; ++nt) {
      bf16x8 vf0 = *(const bf16x8*)&Vs[(nt * 32 + l31) * LDK + 32 + hi * 8];
      o[nt] =
          __builtin_amdgcn_mfma_f32_32x32x16_bf16(pf10, vf0, o[nt], 0, 0, 0);
      bf16x8 vf1 = *(const bf16x8*)&Vs[(nt * 32 + l31) * LDK + 48 + hi * 8];
      o[nt] =
          __builtin_amdgcn_mfma_f32_32x32x16_bf16(pf11, vf1, o[nt], 0, 0, 0);
    }
    __builtin_amdgcn_s_setprio(0);
  }

  // ---- epilogue: row-sum is complete per lane-pair; scale and store ----
  float lg = l_r + __shfl_xor(l_r, 32);  // lanes l/l+32 cover all k-rows
  float linv = 1.f / lg;
  const int b = bh >> 3, h = bh & 7;
#pragma unroll
  for (int r = 0; r < 16; ++r) {
    int row = (r & 3) + 8 * (r >> 2) + 4 * hi;
    float inv = __shfl(linv, row);  // lane `row` owns q = qrow0 + row
    int srow = qt * 128 + wave * 32 + row;
#pragma unroll
    for (int nt = 0; nt < 2; ++nt) {
      out[((size_t)b * SEQ + srow) * E + h * D + nt * 32 + l31] =
          o[nt][r] * inv;
    }
  }
}

// ---------------------------------------------------------------------------
extern "C" void kernel_launch(void* const* d_in, const int* in_sizes, int n_in,
                              void* d_out, int out_size, void* d_ws,
                              size_t ws_size, hipStream_t stream) {
  const float* rot = (const float*)d_in[0];
  const float* ent = (const float*)d_in[1];
  const float* x = (const float*)d_in[2];
  const float* wq = (const float*)d_in[3];
  const float* wk = (const float*)d_in[4];
  const float* wv = (const float*)d_in[5];
  float* out = (float*)d_out;

  const size_t NX = (size_t)BATCH * SEQ * E;  // 4M elements
  ushort* weffbT = (ushort*)d_ws;             // 3*E*E bf16 (1.5 MB)
  ushort* xh = weffbT + 3 * E * E;
  ushort* xl = xh + NX;
  ushort* qg = xl + NX;
  ushort* kg = qg + NX;
  ushort* vtg = kg + NX;

  xcast<<<dim3(NX / 1024), 256, 0, stream>>>(x, xh, xl);
  fold_tiled<<<dim3(E / 256, E / 8, 2), 256, 0, stream>>>(wq, wk, rot, ent,
                                                          weffbT);
  wv_cast<<<dim3(E * E / 1024), 256, 0, stream>>>(wv, weffbT + 2 * E * E);
  qkv_fused<<<dim3(H, BATCH * SEQ / 64), 256, 0, stream>>>(xh, xl, weffbT, qg,
                                                           kg, vtg);
  attn_mfma<<<dim3(SEQ / 128, BATCH * H), 256, 0, stream>>>(qg, kg, vtg, out);
}